// Round 17
// baseline (191.902 us; speedup 1.0000x reference)
//
#include <hip/hip_runtime.h>
#include <hip/hip_fp16.h>
#include <stdint.h>

#define NB 32          // batch size B (fixed by problem)
#define CSHIFT 7       // 128 dst rows per region
#define CROWS 128
#define NC_MAX 1024    // regions: supports M <= 131072
#define FCHUNK 4096    // edges per fill block (halved: grid 391 -> 782)
#define FTHREADS 512   // 8 waves; LDS 52KB -> 3 blocks/CU; 782 blks ~ 3.05/CU
#define EPT (FCHUNK / FTHREADS)      // 8
#define CAP_C 4608     // region capacity: mean 4096 + 8 sigma (overflow->ov)
#define GTHREADS 512   // gather block: 8 waves, 16 half-waves
#define NGW 8          // waves per gather block
#define GEPT ((CAP_C + GTHREADS - 1) / GTHREADS)  // 9 entries/thread
#define HCAP 2816      // sorted-half capacity: mean 2048 + 17 sigma
#define SRC_BITS 18    // N < 262144 (problem: N = 100000)
#define SRC_MASK ((1u << SRC_BITS) - 1)

// meta layout: bits [24:18] = dst & 127 (row-in-region), bits [17:0] = src

// ---------------------------------------------------------------------------
// Fused fill + transpose (one dispatch; the two parts are independent).
// Blocks [0, fblocks): LDS-staged region fill at FCHUNK=4096 -- single-round
//   stage, in-order coalesced csr write (write pattern independent of run
//   length). Region overflow -> ovList (handled by region_sort_gather).
// Blocks [fblocks, ...): x (B,N) f32 -> xt (N,B) f16 32x32 tile transpose
//   (reuses the stage LDS as its tile).
// ---------------------------------------------------------------------------
__global__ __launch_bounds__(FTHREADS) void fill_and_transpose(
        const float* __restrict__ x,
        __half* __restrict__ xt, int N,
        const int* __restrict__ src,
        const int* __restrict__ dst,
        const float* __restrict__ vals,
        int* __restrict__ cCursor,   // [NC_MAX], region-relative, 0-init
        uint2* __restrict__ csr,     // [ncoarse*CAP_C]
        int* __restrict__ ovCount,
        int* __restrict__ ovList,
        int nnz, int fblocks) {
    __shared__ uint2 stage[FCHUNK];          // 32 KB (transpose: tile alias)
    __shared__ unsigned short sbin[FCHUNK];  // 8 KB (0xFFFF = overflow hole)
    __shared__ int lhist[NC_MAX];            // 4 KB: counts -> rank cursors
    __shared__ int lbase[NC_MAX];            // 4 KB: block-local excl base
    __shared__ int delta[NC_MAX];            // 4 KB: global claim - lbase
    int t = threadIdx.x;

    if (blockIdx.x >= fblocks) {
        // ---- transpose part: 32 columns per block, 512 threads ----
        float* tile = (float*)stage;         // [32][33] manual indexing
        int blk = blockIdx.x - fblocks;
        int tx = t & 31, ty = t >> 5;        // ty in 0..15
        int n0 = blk * 32;
        for (int i = ty; i < 32; i += 16) {
            int n = n0 + tx;
            tile[i * 33 + tx] = (n < N) ? x[(size_t)i * N + n] : 0.f;
        }
        __syncthreads();
        for (int i = ty; i < 32; i += 16) {
            int n = n0 + i;
            if (n < N) xt[(size_t)n * NB + tx] =
                __float2half(tile[tx * 33 + i]);
        }
        return;
    }

    // ---- fill part ----
    int e0 = blockIdx.x * FCHUNK;
    int chunk = min(FCHUNK, nnz - e0);
    int      bcache[EPT];   // region bin; -1 = oob
    uint32_t mcache[EPT];   // packed meta
    uint32_t vcache[EPT];   // val bits
    for (int i = t; i < NC_MAX; i += FTHREADS) lhist[i] = 0;
    __syncthreads();
#pragma unroll
    for (int q = 0; q < EPT; ++q) {
        int e = e0 + q * FTHREADS + t;
        if (e < nnz) {
            int d = dst[e];
            int bin = d >> CSHIFT;
            bcache[q] = bin;
            mcache[q] = ((uint32_t)(d & (CROWS - 1)) << SRC_BITS) |
                        (uint32_t)src[e];
            vcache[q] = __float_as_uint(vals[e]);
            atomicAdd(&lhist[bin], 1);
        } else bcache[q] = -1;
    }
    __syncthreads();
    // exclusive scan over 1024 bins: 2 per thread + 512-wide Hillis-Steele
    int s0 = lhist[2 * t];
    int s1 = lhist[2 * t + 1];
    int tsum = s0 + s1;
    lbase[t] = tsum;   // low half as scan workspace
    __syncthreads();
    for (int off = 1; off < FTHREADS; off <<= 1) {
        int add = (t >= off) ? lbase[t - off] : 0;
        __syncthreads();
        lbase[t] += add;
        __syncthreads();
    }
    int texcl = lbase[t] - tsum;
    __syncthreads();           // scan workspace reads done
    lbase[2 * t]     = texcl;
    lbase[2 * t + 1] = texcl + s0;
    {
        int g0 = s0 ? atomicAdd(&cCursor[2 * t], s0) : 0;
        int g1 = s1 ? atomicAdd(&cCursor[2 * t + 1], s1) : 0;
        delta[2 * t]     = g0 - texcl;
        delta[2 * t + 1] = g1 - (texcl + s0);
        lhist[2 * t]     = 0;   // reuse as rank cursors
        lhist[2 * t + 1] = 0;
    }
    __syncthreads();
    // rank claim + scatter into region-sorted LDS stage; overflow -> hole
#pragma unroll
    for (int q = 0; q < EPT; ++q) {
        int bin = bcache[q];
        if (bin >= 0) {
            int r = atomicAdd(&lhist[bin], 1);
            int pos = lbase[bin] + r;
            if (delta[bin] + pos < CAP_C) {
                stage[pos] = make_uint2(mcache[q], vcache[q]);
                sbin[pos] = (unsigned short)bin;
            } else {
                sbin[pos] = 0xFFFF;
                int op = atomicAdd(ovCount, 1);
                ovList[op] = e0 + q * FTHREADS + t;
            }
        }
    }
    __syncthreads();
    // in-order write: consecutive idx -> consecutive global targets per run
    for (int idx = t; idx < chunk; idx += FTHREADS) {
        unsigned short bo = sbin[idx];
        if (bo != 0xFFFF)
            csr[(size_t)bo * CAP_C + delta[bo] + idx] = stage[idx];
    }
}

// ---------------------------------------------------------------------------
// Fused region sort + gather + bias + output-transpose + overflow-fixup.
// One 512-thr block per 128-row region; half-row rounds (r15-proven).
// Overflow edges (ovCount statistically 0 -> one scalar load + skipped
// branch) are applied into the accumulators directly -- no fixup dispatch.
// ---------------------------------------------------------------------------
__global__ __launch_bounds__(GTHREADS) void region_sort_gather(
        const int* __restrict__ cCursor,
        const uint2* __restrict__ cCsr,
        const __half* __restrict__ xt,
        const float* __restrict__ bias,
        const int* __restrict__ ovCount,
        const int* __restrict__ ovList,
        const int* __restrict__ src,
        const int* __restrict__ dst,
        const float* __restrict__ vals,
        float* __restrict__ out, int M) {
    __shared__ uint2 sorted[HCAP];        // 22.5 KB
    __shared__ int whist[NGW][CROWS];     // 4 KB: counts -> abs cursors
    __shared__ int rowOff[CROWS];         // absolute exclusive row base
    __shared__ int rowCnt[CROWS];
    __shared__ int halfBase;              // rowOff[64]
    int c = blockIdx.x;
    int n = min(cCursor[c], CAP_C);
    int t = threadIdx.x;
    int w = t >> 6;                       // wave id 0..7
    int ovN = *ovCount;                   // statistically 0
    uint2 ec[GEPT];
    for (int i = t; i < NGW * CROWS; i += GTHREADS) (&whist[0][0])[i] = 0;
    __syncthreads();
    const uint2* reg = cCsr + (size_t)c * CAP_C;
#pragma unroll
    for (int q = 0; q < GEPT; ++q) {
        int j = q * GTHREADS + t;
        if (j < n) {
            uint2 e = reg[j];
            ec[q] = e;
            atomicAdd(&whist[w][(e.x >> SRC_BITS) & (CROWS - 1)], 1);
        }
    }
    __syncthreads();
    int tot = 0;
    if (t < CROWS) {
#pragma unroll
        for (int w2 = 0; w2 < NGW; ++w2) tot += whist[w2][t];
        rowCnt[t] = tot;
        rowOff[t] = tot;
    }
    __syncthreads();
    for (int off = 1; off < CROWS; off <<= 1) {
        int add = (t < CROWS && t >= off) ? rowOff[t - off] : 0;
        __syncthreads();
        if (t < CROWS) rowOff[t] += add;
        __syncthreads();
    }
    if (t < CROWS) {
        int excl = rowOff[t] - rowCnt[t];
        rowOff[t] = excl;
        if (t == 64) halfBase = excl;     // = count of rows 0..63
        int run = excl;
#pragma unroll
        for (int w2 = 0; w2 < NGW; ++w2) {
            int cn = whist[w2][t];
            whist[w2][t] = run;           // absolute cursor for (wave,row)
            run += cn;
        }
    }
    __syncthreads();
    int g = t >> 5;                       // half-wave id 0..15
    int b = t & 31;                       // batch lane
    int half0 = halfBase;
    int half1 = n - halfBase;

    if (half0 <= HCAP && half1 <= HCAP) {
        for (int h = 0; h < 2; ++h) {
            int hb = h ? halfBase : 0;
#pragma unroll
            for (int q = 0; q < GEPT; ++q) {
                int j = q * GTHREADS + t;
                if (j < n) {
                    int row = (ec[q].x >> SRC_BITS) & (CROWS - 1);
                    if ((row >> 6) == h) {
                        int p = atomicAdd(&whist[w][row], 1) - hb;
                        sorted[p] = ec[q];
                    }
                }
            }
            __syncthreads();
            for (int r = (h << 6) + g; r < (h << 6) + 64; r += 16) {
                int m = c * CROWS + r;
                if (m >= M) continue;
                int jj   = rowOff[r] - hb;
                int jend = jj + rowCnt[r];
                float acc0 = 0.f, acc1 = 0.f;
                for (; jj + 8 <= jend; jj += 8) {
                    uint2 e0 = sorted[jj + 0];
                    uint2 e1 = sorted[jj + 1];
                    uint2 e2 = sorted[jj + 2];
                    uint2 e3 = sorted[jj + 3];
                    uint2 e4 = sorted[jj + 4];
                    uint2 e5 = sorted[jj + 5];
                    uint2 e6 = sorted[jj + 6];
                    uint2 e7 = sorted[jj + 7];
                    float x0 = __half2float(xt[(size_t)(e0.x & SRC_MASK) * NB + b]);
                    float x1 = __half2float(xt[(size_t)(e1.x & SRC_MASK) * NB + b]);
                    float x2 = __half2float(xt[(size_t)(e2.x & SRC_MASK) * NB + b]);
                    float x3 = __half2float(xt[(size_t)(e3.x & SRC_MASK) * NB + b]);
                    float x4 = __half2float(xt[(size_t)(e4.x & SRC_MASK) * NB + b]);
                    float x5 = __half2float(xt[(size_t)(e5.x & SRC_MASK) * NB + b]);
                    float x6 = __half2float(xt[(size_t)(e6.x & SRC_MASK) * NB + b]);
                    float x7 = __half2float(xt[(size_t)(e7.x & SRC_MASK) * NB + b]);
                    acc0 = fmaf(__uint_as_float(e0.y), x0, acc0);
                    acc1 = fmaf(__uint_as_float(e1.y), x1, acc1);
                    acc0 = fmaf(__uint_as_float(e2.y), x2, acc0);
                    acc1 = fmaf(__uint_as_float(e3.y), x3, acc1);
                    acc0 = fmaf(__uint_as_float(e4.y), x4, acc0);
                    acc1 = fmaf(__uint_as_float(e5.y), x5, acc1);
                    acc0 = fmaf(__uint_as_float(e6.y), x6, acc0);
                    acc1 = fmaf(__uint_as_float(e7.y), x7, acc1);
                }
                for (; jj < jend; ++jj) {
                    uint2 e = sorted[jj];
                    acc0 = fmaf(__uint_as_float(e.y),
                                __half2float(xt[(size_t)(e.x & SRC_MASK) * NB + b]),
                                acc0);
                }
                if (ovN) {                 // statistically never taken
                    for (int k = 0; k < ovN; ++k) {
                        int e = ovList[k];
                        if (dst[e] == m)
                            acc0 = fmaf(vals[e],
                                __half2float(xt[(size_t)src[e] * NB + b]),
                                acc0);
                    }
                }
                out[(size_t)b * M + m] = acc0 + acc1 + bias[m];
            }
            __syncthreads();   // protect sorted[] before next round
        }
    } else {
        // slow path (arbitrary skew): per-row scan of the L2-resident region
        for (int r = g; r < CROWS; r += 16) {
            int m = c * CROWS + r;
            if (m >= M) continue;
            float acc = 0.f;
            for (int j = 0; j < n; ++j) {
                uint2 e = reg[j];
                if ((int)((e.x >> SRC_BITS) & (CROWS - 1)) == r)
                    acc = fmaf(__uint_as_float(e.y),
                               __half2float(xt[(size_t)(e.x & SRC_MASK) * NB + b]),
                               acc);
            }
            if (ovN) {
                for (int k = 0; k < ovN; ++k) {
                    int e = ovList[k];
                    if (dst[e] == m)
                        acc = fmaf(vals[e],
                            __half2float(xt[(size_t)src[e] * NB + b]), acc);
                }
            }
            out[(size_t)b * M + m] = acc + bias[m];
        }
    }
}

// ---------------------------------------------------------------------------
// Fallback path kernels (used only if ws/geometry checks fail).
// ---------------------------------------------------------------------------
__global__ void transpose_x_kernel(const float* __restrict__ x,
                                   __half* __restrict__ xt, int N) {
    __shared__ float tile[32][33];
    int n0 = blockIdx.x * 32;
    for (int i = threadIdx.y; i < 32; i += 8) {
        int n = n0 + threadIdx.x;
        tile[i][threadIdx.x] = (n < N) ? x[(size_t)i * N + n] : 0.f;
    }
    __syncthreads();
    for (int i = threadIdx.y; i < 32; i += 8) {
        int n = n0 + i;
        if (n < N) xt[(size_t)n * NB + threadIdx.x] =
            __float2half(tile[threadIdx.x][i]);
    }
}

__global__ void scatter_kernel(const int* __restrict__ src,
                               const int* __restrict__ dst,
                               const float* __restrict__ vals,
                               const __half* __restrict__ xt,
                               float* __restrict__ yt, int nnz) {
    long long tid = (long long)blockIdx.x * blockDim.x + threadIdx.x;
    int e = (int)(tid >> 5);
    if (e >= nnz) return;
    int b = (int)(tid & 31);
    atomicAdd(&yt[(size_t)dst[e] * NB + b],
              vals[e] * __half2float(xt[(size_t)src[e] * NB + b]));
}

__global__ void finalize_kernel(const float* __restrict__ yt,
                                const float* __restrict__ bias,
                                float* __restrict__ out, int M) {
    __shared__ float tile[32][33];
    int m0 = blockIdx.x * 32;
    for (int i = threadIdx.y; i < 32; i += 8) {
        int m = m0 + i;
        tile[i][threadIdx.x] = (m < M) ? yt[(size_t)m * NB + threadIdx.x] : 0.f;
    }
    __syncthreads();
    for (int i = threadIdx.y; i < 32; i += 8) {
        int m = m0 + threadIdx.x;
        if (m < M) out[(size_t)i * M + m] = tile[threadIdx.x][i] + bias[m];
    }
}

extern "C" void kernel_launch(void* const* d_in, const int* in_sizes, int n_in,
                              void* d_out, int out_size, void* d_ws, size_t ws_size,
                              hipStream_t stream) {
    const float* x       = (const float*)d_in[0];   // (B, N, 1) fp32
    const int*   indices = (const int*)  d_in[1];   // (2, NNZ) int32
    const float* vals    = (const float*)d_in[2];   // (NNZ,) fp32
    const float* bias    = (const float*)d_in[3];   // (M, 1) fp32

    float* out = (float*)d_out;                     // (B, M, 1) fp32

    int nnz = in_sizes[1] / 2;
    int N   = in_sizes[0] / NB;
    int M   = in_sizes[3];

    const int* src = indices;        // row 0
    const int* dst = indices + nnz;  // row 1

    int ncoarse = (M + CROWS - 1) >> CSHIFT;   // 782 for M=100000

    // primary workspace layout (~48 MB):
    //   xt       N*NB f16                (6.4 MB)
    //   cCursor  NC_MAX i32              | zeroed by one small memset
    //   ovCount  4 i32                   |
    //   ovList   nnz i32                 (12.8 MB)
    //   cCsr     ncoarse*CAP_C uint2     (28.8 MB)
    __half* xt      = (__half*)d_ws;
    int*    cCursor = (int*)(xt + (size_t)N * NB);
    int*    ovCount = cCursor + NC_MAX;
    int*    ovList  = ovCount + 4;
    uint2*  cCsr    = (uint2*)(((uintptr_t)(ovList + nnz) + 15) &
                               ~(uintptr_t)15);

    size_t need = (size_t)((char*)(cCsr + (size_t)ncoarse * CAP_C) -
                           (char*)d_ws);

    // fallback layout: yt immediately after xt (paths are exclusive)
    float* yt = (float*)(xt + (size_t)N * NB);
    size_t need_fb = (size_t)((char*)(yt + (size_t)M * NB) - (char*)d_ws);

    if (ws_size >= need && ncoarse <= NC_MAX) {
        hipMemsetAsync(cCursor, 0, (NC_MAX + 4) * sizeof(int), stream);
        int fblocks = (nnz + FCHUNK - 1) / FCHUNK;  // 782
        int tblocks = (N + 31) / 32;                // 3125
        fill_and_transpose<<<fblocks + tblocks, FTHREADS, 0, stream>>>(
            x, xt, N, src, dst, vals, cCursor, cCsr, ovCount, ovList,
            nnz, fblocks);
        region_sort_gather<<<ncoarse, GTHREADS, 0, stream>>>(
            cCursor, cCsr, xt, bias, ovCount, ovList, src, dst, vals, out, M);
    } else if (ws_size >= need_fb) {
        transpose_x_kernel<<<(N + 31) / 32, dim3(32, 8), 0, stream>>>(x, xt, N);
        hipMemsetAsync(yt, 0, (size_t)M * NB * sizeof(float), stream);
        long long pairs = (long long)nnz * NB;
        int grid = (int)((pairs + 255) / 256);
        scatter_kernel<<<grid, 256, 0, stream>>>(src, dst, vals, xt, yt, nnz);
        finalize_kernel<<<(M + 31) / 32, dim3(32, 8), 0, stream>>>(yt, bias,
                                                                   out, M);
    }
}